// Round 1
// baseline (245.572 us; speedup 1.0000x reference)
//
#include <hip/hip_runtime.h>

#define NN 50000
#define NE 800000
#define CAP 64        // 2 shards x 32 slots
#define NPAD 50176    // counter array stride (line-separated shards)
#define SLICE 6250    // NN / 8 nodes per XCD slice

typedef unsigned int   u32;
typedef unsigned short u16;
typedef __attribute__((ext_vector_type(8))) short short8;  // 8 bf16 in 4 VGPRs
typedef __attribute__((ext_vector_type(4))) float f32x4;

__device__ inline u16 f2bf(float f) {
    u32 u = __float_as_uint(f);
    return (u16)((u + 0x7FFF + ((u >> 16) & 1)) >> 16);   // RNE
}
__device__ inline float bfval(u16 h) { return __uint_as_float(((u32)h) << 16); }
__device__ inline float bf_lo(u32 u) { return __uint_as_float(u << 16); }
__device__ inline float bf_hi(u32 u) { return __uint_as_float(u & 0xFFFF0000u); }

// ---------------- graph build (XCD-sliced, 2-way sharded counters) ----------

__global__ __launch_bounds__(256) void build_ell(const int* __restrict__ ei,
                                                 int* __restrict__ cnt,
                                                 u16* __restrict__ ell) {
    const int s  = blockIdx.x & 7;
    const int g  = blockIdx.x >> 3;
    const int ng = gridDim.x >> 3;
    const int lo = s * SLICE, hi = lo + SLICE;
    for (int e0 = (g * 256 + (int)threadIdx.x) * 4; e0 < NE; e0 += ng * 1024) {
        int4 d4 = *(const int4*)(ei + NE + e0);
        int dv[4] = {d4.x, d4.y, d4.z, d4.w};
#pragma unroll
        for (int k = 0; k < 4; ++k) {
            int d = dv[k];
            if (d >= lo && d < hi) {
                int src = ei[e0 + k];
                int sh = k & 1;
                int pos = atomicAdd(&cnt[sh * NPAD + d], 1);
                if (pos < 32) ell[d * CAP + sh * 32 + pos] = (u16)src;
            }
        }
    }
}

// ---------------- W pre-swizzle + counter zeroing ----------------

__global__ __launch_bounds__(256) void prep_w(const float* __restrict__ W1,
                                              const float* __restrict__ W2,
                                              u16* __restrict__ W1h, u16* __restrict__ W1l,
                                              u16* __restrict__ W2h, u16* __restrict__ W2l,
                                              int* __restrict__ cnt) {
    int i = blockIdx.x * 256 + threadIdx.x;           // grid 128 -> 32768 threads
    for (int z = i; z < 2 * NPAD; z += 32768) cnt[z] = 0;
    const float* W; u16 *Dh, *Dl; int NOUT, idx;
    if (i < 16384) { W = W1; Dh = W1h; Dl = W1l; NOUT = 128; idx = i; }
    else           { idx = i - 16384; if (idx >= 8192) return;
                     W = W2; Dh = W2h; Dl = W2l; NOUT = 64; }
    int j = idx & 7, l = (idx >> 3) & 63, kc = (idx >> 9) & 3, t = idx >> 11;
    int k = kc * 32 + (l >> 4) * 8 + j;
    int n = t * 16 + (l & 15);
    float w = W[k * NOUT + n];
    u16 h = f2bf(w);
    Dh[idx] = h;
    Dl[idx] = f2bf(w - bfval(h));
}

// ---------------- MFMA GEMM, K=128, fp32 A via 3-term bf16 split ------------
// C written CHUNK-MAJOR: [NOUT/32][NN][32] so aggregation slices are contiguous.
// degT epilogue: total degree (+self) per node, consumed by build_norm.

template <int NOUT>
__global__ __launch_bounds__(256) void gemm_mfma(const float* __restrict__ A,
                                                 const u16* __restrict__ Wh,
                                                 const u16* __restrict__ Wl,
                                                 u16* __restrict__ C, int M,
                                                 const int* __restrict__ cnt,
                                                 u16* __restrict__ degT) {
    constexpr int NT = NOUT / 16;
    const int tid = threadIdx.x;

    if (tid < 64) {                       // independent degT epilogue (free)
        int node = blockIdx.x * 64 + tid;
        if (node < NN) degT[node] = (u16)(cnt[node] + cnt[NPAD + node] + 1);
    }

    const int w = tid >> 6, l = tid & 63;
    const int m = l & 15, q = l >> 4;

    int arow = blockIdx.x * 64 + w * 16 + m;
    const float* Ar = A + (size_t)min(arow, M - 1) * 128;

    f32x4 acc[NT] = {};

#pragma unroll
    for (int kc = 0; kc < 4; ++kc) {
        float p[8];
        *(float4*)&p[0] = *(const float4*)(Ar + kc * 32 + q * 8);
        *(float4*)&p[4] = *(const float4*)(Ar + kc * 32 + q * 8 + 4);
        short8 ah, al;
#pragma unroll
        for (int j = 0; j < 8; ++j) {
            u16 h = f2bf(p[j]);
            ah[j] = (short)h;
            al[j] = (short)f2bf(p[j] - bfval(h));
        }
#pragma unroll
        for (int t = 0; t < NT; ++t) {
            size_t bo = ((size_t)(t * 4 + kc) * 64 + l) * 8;
            short8 bh = *(const short8*)(Wh + bo);
            short8 bl = *(const short8*)(Wl + bo);
            acc[t] = __builtin_amdgcn_mfma_f32_16x16x32_bf16(ah, bh, acc[t], 0, 0, 0);
            acc[t] = __builtin_amdgcn_mfma_f32_16x16x32_bf16(al, bh, acc[t], 0, 0, 0);
            acc[t] = __builtin_amdgcn_mfma_f32_16x16x32_bf16(ah, bl, acc[t], 0, 0, 0);
        }
    }

    int growbase = blockIdx.x * 64 + w * 16 + q * 4;
#pragma unroll
    for (int t = 0; t < NT; ++t)
#pragma unroll
        for (int r = 0; r < 4; ++r) {
            int grow = growbase + r;
            if (grow < M)
                C[(size_t)(t >> 1) * NN * 32 + (size_t)grow * 32 + (t & 1) * 16 + m] =
                    f2bf(acc[t][r]);
        }
}

// ---- MFMA GEMM, K=128, bf16 A (exact 2-term), A chunk-major [4][NN][32] ----

__global__ __launch_bounds__(256) void gemm_mfma_bf(const u16* __restrict__ A,
                                                    const u16* __restrict__ Wh,
                                                    const u16* __restrict__ Wl,
                                                    u16* __restrict__ C, int M) {
    constexpr int NT = 4;
    const int tid = threadIdx.x;
    const int w = tid >> 6, l = tid & 63;
    const int m = l & 15, q = l >> 4;

    int arow = blockIdx.x * 64 + w * 16 + m;
    const size_t ar = (size_t)min(arow, M - 1) * 32;

    f32x4 acc[NT] = {};

#pragma unroll
    for (int kc = 0; kc < 4; ++kc) {
        short8 ah = *(const short8*)(A + (size_t)kc * NN * 32 + ar + q * 8);
#pragma unroll
        for (int t = 0; t < NT; ++t) {
            size_t bo = ((size_t)(t * 4 + kc) * 64 + l) * 8;
            short8 bh = *(const short8*)(Wh + bo);
            short8 bl = *(const short8*)(Wl + bo);
            acc[t] = __builtin_amdgcn_mfma_f32_16x16x32_bf16(ah, bh, acc[t], 0, 0, 0);
            acc[t] = __builtin_amdgcn_mfma_f32_16x16x32_bf16(ah, bl, acc[t], 0, 0, 0);
        }
    }

    int growbase = blockIdx.x * 64 + w * 16 + q * 4;
#pragma unroll
    for (int t = 0; t < NT; ++t)
#pragma unroll
        for (int r = 0; r < 4; ++r) {
            int grow = growbase + r;
            if (grow < M)
                C[(size_t)(t >> 1) * NN * 32 + (size_t)grow * 32 + (t & 1) * 16 + m] =
                    f2bf(acc[t][r]);
        }
}

// ---------------- one-shot edge normalization pass --------------------------
// Compacts sharded ELL into per-lane (src, norm) arrays + per-node edge count,
// folding the self-loop. Hoists the scattered degree lookups + rsqrt out of
// the per-chunk aggregation loops. norm kept fp32 (bit-identical to before).

__global__ __launch_bounds__(256) void build_norm(const int* __restrict__ cnt,
                                                  const u16* __restrict__ ell,
                                                  const u16* __restrict__ degT,
                                                  u16* __restrict__ els,
                                                  float* __restrict__ nrm,
                                                  int* __restrict__ mArr) {
    const int tid = threadIdx.x;
    const int node = (int)((blockIdx.x * 256 + tid) >> 6);
    if (node >= NN) return;
    const int lane = tid & 63;

    const int c0r = cnt[node], c1r = cnt[NPAD + node];
    const int c0 = min(c0r, 32), c1 = min(c1r, 32);
    const int ne = min(c0 + c1, 63);        // keep one lane for self-loop
    const float di = rsqrtf((float)(c0r + c1r + 1));
    int slot = (lane < c0) ? lane : 32 + (lane - c0);
    int   s_l = (lane < ne) ? (int)ell[(size_t)node * CAP + slot] : node;
    float n_l = (lane <= ne) ? rsqrtf((float)degT[s_l]) * di : 0.0f;

    els[(size_t)node * 64 + lane] = (u16)s_l;
    nrm[(size_t)node * 64 + lane] = n_l;
    if (lane == 0) mArr[node] = ne + 1;
}

// ---------------- chunked normalized aggregation ----------------------------
// One wave per (node, 32-feature chunk). H is chunk-major [NCH][NN][32] bf16:
// each edge-gather touches exactly one 64B line of a 3.2MB slice that fits the
// per-XCD 4MB L2. Grid is chunk-outer so co-resident blocks share the slice.

template <int NCH, bool RELU, bool OUTBF>
__global__ __launch_bounds__(256) void aggregate_ch(const u16* __restrict__ H,
                                                    const u16* __restrict__ els,
                                                    const float* __restrict__ nrm,
                                                    const int* __restrict__ mArr,
                                                    const float* __restrict__ bias,
                                                    void* __restrict__ outp) {
    constexpr int NB = (NN + 3) / 4;        // node-blocks per chunk
    const int tid = threadIdx.x;
    const int chunk = blockIdx.x / NB;
    const int nb = blockIdx.x - chunk * NB;
    const int node = nb * 4 + (tid >> 6);
    if (node >= NN) return;
    const int lane = tid & 63;
    const int g = lane >> 3, ci = lane & 7;  // 8 edges/step, 8 lanes (4 feat) each

    const int m = mArr[node];
    const int mPad = (m + 15) & ~15;
    int   s_l = (int)els[(size_t)node * 64 + lane];
    float n_l = nrm[(size_t)node * 64 + lane];

    const u16* Hc = H + (size_t)chunk * NN * 32;
    float acc[4] = {0, 0, 0, 0};
    for (int j = 0; j < mPad; j += 16) {
        int   sA = __shfl(s_l, j + g);
        float nA = __shfl(n_l, j + g);
        int   sB = __shfl(s_l, j + 8 + g);
        float nB = __shfl(n_l, j + 8 + g);
        uint2 vA = *(const uint2*)(Hc + (size_t)sA * 32 + ci * 4);
        uint2 vB = *(const uint2*)(Hc + (size_t)sB * 32 + ci * 4);
        acc[0] += nA * bf_lo(vA.x); acc[1] += nA * bf_hi(vA.x);
        acc[2] += nA * bf_lo(vA.y); acc[3] += nA * bf_hi(vA.y);
        acc[0] += nB * bf_lo(vB.x); acc[1] += nB * bf_hi(vB.x);
        acc[2] += nB * bf_lo(vB.y); acc[3] += nB * bf_hi(vB.y);
    }

#pragma unroll
    for (int i = 0; i < 4; ++i) {            // reduce over g (lane bits 3..5)
        acc[i] += __shfl_xor(acc[i], 8);
        acc[i] += __shfl_xor(acc[i], 16);
        acc[i] += __shfl_xor(acc[i], 32);
    }

    if (lane < 8) {
        float4 b4 = *(const float4*)(bias + chunk * 32 + lane * 4);
        float4 o = make_float4(acc[0] + b4.x, acc[1] + b4.y,
                               acc[2] + b4.z, acc[3] + b4.w);
        if (RELU) { o.x = fmaxf(o.x, 0.f); o.y = fmaxf(o.y, 0.f);
                    o.z = fmaxf(o.z, 0.f); o.w = fmaxf(o.w, 0.f); }
        if (OUTBF) {                          // chunk-major bf16 [NCH][NN][32]
            u16* out = (u16*)outp;
            *(ushort4*)(out + (size_t)chunk * NN * 32 + (size_t)node * 32 + lane * 4) =
                make_ushort4(f2bf(o.x), f2bf(o.y), f2bf(o.z), f2bf(o.w));
        } else {                              // row-major fp32 [NN][NCH*32]
            float* out = (float*)outp;
            *(float4*)(out + (size_t)node * (NCH * 32) + chunk * 32 + lane * 4) = o;
        }
    }
}

// ---------------- launch ----------------

extern "C" void kernel_launch(void* const* d_in, const int* in_sizes, int n_in,
                              void* d_out, int out_size, void* d_ws, size_t ws_size,
                              hipStream_t stream) {
    const float* x  = (const float*)d_in[0];
    const int*   ei = (const int*)d_in[1];
    const float* W1 = (const float*)d_in[2];
    const float* b1 = (const float*)d_in[3];
    const float* W2 = (const float*)d_in[4];
    const float* b2 = (const float*)d_in[5];
    float* out = (float*)d_out;

    char* ws = (char*)d_ws;
    size_t off = 0;
    int* cnt = (int*)ws;                     off += (size_t)2 * NPAD * 4;
    u16* ell = (u16*)(ws + off);             off += (size_t)NN * CAP * 2;
    off = (off + 255) & ~(size_t)255;
    u16* W1h = (u16*)(ws + off);             off += 16384 * 2;
    u16* W1l = (u16*)(ws + off);             off += 16384 * 2;
    u16* W2h = (u16*)(ws + off);             off += 8192 * 2;
    u16* W2l = (u16*)(ws + off);             off += 8192 * 2;
    off = (off + 255) & ~(size_t)255;
    u16* els = (u16*)(ws + off);             off += (size_t)NN * 64 * 2;
    float* nrm = (float*)(ws + off);         off += (size_t)NN * 64 * 4;
    int* mArr = (int*)(ws + off);            off += (size_t)NN * 4;
    u16* degT = (u16*)(ws + off);            off += (size_t)NN * 2;
    off = (off + 255) & ~(size_t)255;
    u16* Hbf = (u16*)(ws + off);             off += (size_t)NN * 128 * 2;  // H1 / H2
    u16* Abf = (u16*)(ws + off);             off += (size_t)NN * 128 * 2;  // agg1 out

    prep_w<<<128, 256, 0, stream>>>(W1, W2, W1h, W1l, W2h, W2l, cnt);
    build_ell<<<1600, 256, 0, stream>>>(ei, cnt, ell);

    // layer 1: H1 = x@W1 (bf16, chunk-major) + degT epilogue
    gemm_mfma<128><<<(NN + 63) / 64, 256, 0, stream>>>(x, W1h, W1l, Hbf, NN, cnt, degT);
    // one-shot per-edge (src, norm) compaction
    build_norm<<<(NN + 3) / 4, 256, 0, stream>>>(cnt, ell, degT, els, nrm, mArr);
    // agg+bias+relu -> Abf (bf16, chunk-major), L2-resident 32-feature slices
    aggregate_ch<4, true, true><<<4 * ((NN + 3) / 4), 256, 0, stream>>>(
        Hbf, els, nrm, mArr, b1, Abf);

    // layer 2: H2 = Abf@W2 (bf16 exact 2-term, chunk-major in/out)
    gemm_mfma_bf<<<(NN + 63) / 64, 256, 0, stream>>>(Abf, W2h, W2l, Hbf, NN);
    // agg+bias -> out (fp32 row-major)
    aggregate_ch<2, false, false><<<2 * ((NN + 3) / 4), 256, 0, stream>>>(
        Hbf, els, nrm, mArr, b2, out);
}

// Round 2
// 240.356 us; speedup vs baseline: 1.0217x; 1.0217x over previous
//
#include <hip/hip_runtime.h>

#define NN 50000
#define NE 800000
#define CAP 64        // 2 shards x 32 slots
#define NPAD 50176    // counter array stride (line-separated shards)
#define SLICE 6250    // NN / 8 nodes per XCD slice

typedef unsigned int   u32;
typedef unsigned short u16;
typedef __attribute__((ext_vector_type(8))) short short8;  // 8 bf16 in 4 VGPRs
typedef __attribute__((ext_vector_type(4))) float f32x4;

__device__ inline u16 f2bf(float f) {
    u32 u = __float_as_uint(f);
    return (u16)((u + 0x7FFF + ((u >> 16) & 1)) >> 16);   // RNE
}
__device__ inline float bfval(u16 h) { return __uint_as_float(((u32)h) << 16); }

// ---------------- graph build (XCD-sliced, 2-way sharded counters) ----------

__global__ __launch_bounds__(256) void build_ell(const int* __restrict__ ei,
                                                 int* __restrict__ cnt,
                                                 u16* __restrict__ ell) {
    const int s  = blockIdx.x & 7;
    const int g  = blockIdx.x >> 3;
    const int ng = gridDim.x >> 3;
    const int lo = s * SLICE, hi = lo + SLICE;
    for (int e0 = (g * 256 + (int)threadIdx.x) * 4; e0 < NE; e0 += ng * 1024) {
        int4 d4 = *(const int4*)(ei + NE + e0);
        int dv[4] = {d4.x, d4.y, d4.z, d4.w};
#pragma unroll
        for (int k = 0; k < 4; ++k) {
            int d = dv[k];
            if (d >= lo && d < hi) {
                int src = ei[e0 + k];
                int sh = k & 1;
                int pos = atomicAdd(&cnt[sh * NPAD + d], 1);
                if (pos < 32) ell[d * CAP + sh * 32 + pos] = (u16)src;
            }
        }
    }
}

// ---------------- W pre-swizzle + counter zeroing ----------------

__global__ __launch_bounds__(256) void prep_w(const float* __restrict__ W1,
                                              const float* __restrict__ W2,
                                              u16* __restrict__ W1h, u16* __restrict__ W1l,
                                              u16* __restrict__ W2h, u16* __restrict__ W2l,
                                              int* __restrict__ cnt) {
    int i = blockIdx.x * 256 + threadIdx.x;           // grid 128 -> 32768 threads
    for (int z = i; z < 2 * NPAD; z += 32768) cnt[z] = 0;
    const float* W; u16 *Dh, *Dl; int NOUT, idx;
    if (i < 16384) { W = W1; Dh = W1h; Dl = W1l; NOUT = 128; idx = i; }
    else           { idx = i - 16384; if (idx >= 8192) return;
                     W = W2; Dh = W2h; Dl = W2l; NOUT = 64; }
    int j = idx & 7, l = (idx >> 3) & 63, kc = (idx >> 9) & 3, t = idx >> 11;
    int k = kc * 32 + (l >> 4) * 8 + j;
    int n = t * 16 + (l & 15);
    float w = W[k * NOUT + n];
    u16 h = f2bf(w);
    Dh[idx] = h;
    Dl[idx] = f2bf(w - bfval(h));
}

// ---------------- MFMA GEMM, K=128, fp32 A via 3-term bf16 split ------------
// Output fp32 row-major [M][128] (feeds fp32 aggregation — no extracts there).
// degT epilogue: total degree (+self) per node, consumed by build_norm.

__global__ __launch_bounds__(256) void gemm_mfma1(const float* __restrict__ A,
                                                  const u16* __restrict__ Wh,
                                                  const u16* __restrict__ Wl,
                                                  float* __restrict__ C, int M,
                                                  const int* __restrict__ cnt,
                                                  u16* __restrict__ degT) {
    constexpr int NT = 8;
    const int tid = threadIdx.x;

    if (tid < 64) {                       // independent degT epilogue (free)
        int node = blockIdx.x * 64 + tid;
        if (node < NN) degT[node] = (u16)(cnt[node] + cnt[NPAD + node] + 1);
    }

    const int w = tid >> 6, l = tid & 63;
    const int m = l & 15, q = l >> 4;

    int arow = blockIdx.x * 64 + w * 16 + m;
    const float* Ar = A + (size_t)min(arow, M - 1) * 128;

    f32x4 acc[NT] = {};

#pragma unroll
    for (int kc = 0; kc < 4; ++kc) {
        float p[8];
        *(float4*)&p[0] = *(const float4*)(Ar + kc * 32 + q * 8);
        *(float4*)&p[4] = *(const float4*)(Ar + kc * 32 + q * 8 + 4);
        short8 ah, al;
#pragma unroll
        for (int j = 0; j < 8; ++j) {
            u16 h = f2bf(p[j]);
            ah[j] = (short)h;
            al[j] = (short)f2bf(p[j] - bfval(h));
        }
#pragma unroll
        for (int t = 0; t < NT; ++t) {
            size_t bo = ((size_t)(t * 4 + kc) * 64 + l) * 8;
            short8 bh = *(const short8*)(Wh + bo);
            short8 bl = *(const short8*)(Wl + bo);
            acc[t] = __builtin_amdgcn_mfma_f32_16x16x32_bf16(ah, bh, acc[t], 0, 0, 0);
            acc[t] = __builtin_amdgcn_mfma_f32_16x16x32_bf16(al, bh, acc[t], 0, 0, 0);
            acc[t] = __builtin_amdgcn_mfma_f32_16x16x32_bf16(ah, bl, acc[t], 0, 0, 0);
        }
    }

    int growbase = blockIdx.x * 64 + w * 16 + q * 4;
#pragma unroll
    for (int t = 0; t < NT; ++t)
#pragma unroll
        for (int r = 0; r < 4; ++r) {
            int grow = growbase + r;
            if (grow < M) C[(size_t)grow * 128 + t * 16 + m] = acc[t][r];
        }
}

// ---- MFMA GEMM, K=128, bf16 A (exact 2-term), fp32 out [M][64] -------------

__global__ __launch_bounds__(256) void gemm_mfma_bf(const u16* __restrict__ A,
                                                    const u16* __restrict__ Wh,
                                                    const u16* __restrict__ Wl,
                                                    float* __restrict__ C, int M) {
    constexpr int NT = 4;
    const int tid = threadIdx.x;
    const int w = tid >> 6, l = tid & 63;
    const int m = l & 15, q = l >> 4;

    int arow = blockIdx.x * 64 + w * 16 + m;
    const u16* Ar = A + (size_t)min(arow, M - 1) * 128;

    f32x4 acc[NT] = {};

#pragma unroll
    for (int kc = 0; kc < 4; ++kc) {
        short8 ah = *(const short8*)(Ar + kc * 32 + q * 8);
#pragma unroll
        for (int t = 0; t < NT; ++t) {
            size_t bo = ((size_t)(t * 4 + kc) * 64 + l) * 8;
            short8 bh = *(const short8*)(Wh + bo);
            short8 bl = *(const short8*)(Wl + bo);
            acc[t] = __builtin_amdgcn_mfma_f32_16x16x32_bf16(ah, bh, acc[t], 0, 0, 0);
            acc[t] = __builtin_amdgcn_mfma_f32_16x16x32_bf16(ah, bl, acc[t], 0, 0, 0);
        }
    }

    int growbase = blockIdx.x * 64 + w * 16 + q * 4;
#pragma unroll
    for (int t = 0; t < NT; ++t)
#pragma unroll
        for (int r = 0; r < 4; ++r) {
            int grow = growbase + r;
            if (grow < M) C[(size_t)grow * 64 + t * 16 + m] = acc[t][r];
        }
}

// ---------------- one-shot edge normalization pass --------------------------
// Compacts sharded ELL into per-lane (src, norm) arrays + per-node edge count,
// folding the self-loop. Hoists the scattered degree lookups + rsqrt out of
// the aggregation kernels. norm fp32 (bit-identical to inline computation).

__global__ __launch_bounds__(256) void build_norm(const int* __restrict__ cnt,
                                                  const u16* __restrict__ ell,
                                                  const u16* __restrict__ degT,
                                                  u16* __restrict__ els,
                                                  float* __restrict__ nrm,
                                                  int* __restrict__ mArr) {
    const int tid = threadIdx.x;
    const int node = (int)((blockIdx.x * 256 + tid) >> 6);
    if (node >= NN) return;
    const int lane = tid & 63;

    const int c0r = cnt[node], c1r = cnt[NPAD + node];
    const int c0 = min(c0r, 32), c1 = min(c1r, 32);
    const int ne = min(c0 + c1, 63);        // keep one lane for self-loop
    const float di = rsqrtf((float)(c0r + c1r + 1));
    int slot = (lane < c0) ? lane : 32 + (lane - c0);
    int   s_l = (lane < ne) ? (int)ell[(size_t)node * CAP + slot] : node;
    float n_l = (lane <= ne) ? rsqrtf((float)degT[s_l]) * di : 0.0f;

    els[(size_t)node * 64 + lane] = (u16)s_l;
    nrm[(size_t)node * 64 + lane] = n_l;
    if (lane == 0) mArr[node] = ne + 1;
}

// ---------------- normalized aggregation (one wave per node, fp32 H) --------
// Pure-FMA inner loop: float4 gathers, no bf16 extracts. Valid lanes beyond m
// carry n=0 / s=node so padded gathers are harmless.

template <int F, bool RELU, bool OUTBF>
__global__ __launch_bounds__(256) void aggregate_f(const float* __restrict__ H,
                                                   const u16* __restrict__ els,
                                                   const float* __restrict__ nrm,
                                                   const int* __restrict__ mArr,
                                                   const float* __restrict__ bias,
                                                   void* __restrict__ outp) {
    const int tid = threadIdx.x;
    const int node = (int)((blockIdx.x * 256 + tid) >> 6);
    if (node >= NN) return;
    const int lane = tid & 63;

    constexpr int L = F / 4;          // lanes per edge (float4 each): 32 / 16
    constexpr int G = 64 / L;         // edges gathered per group: 2 / 4
    const int g = lane / L;
    const int ci = lane & (L - 1);

    const int m = mArr[node];
    const int mPad = (m + 2 * G - 1) & ~(2 * G - 1);
    int   s_l = (int)els[(size_t)node * 64 + lane];
    float n_l = nrm[(size_t)node * 64 + lane];

    float acc[4] = {0, 0, 0, 0};
    for (int j = 0; j < mPad; j += 2 * G) {
        int   sA = __shfl(s_l, j + g);
        float nA = __shfl(n_l, j + g);
        int   sB = __shfl(s_l, j + G + g);
        float nB = __shfl(n_l, j + G + g);
        float4 vA = *(const float4*)(H + (size_t)sA * F + ci * 4);
        float4 vB = *(const float4*)(H + (size_t)sB * F + ci * 4);
        acc[0] += nA * vA.x; acc[1] += nA * vA.y;
        acc[2] += nA * vA.z; acc[3] += nA * vA.w;
        acc[0] += nB * vB.x; acc[1] += nB * vB.y;
        acc[2] += nB * vB.z; acc[3] += nB * vB.w;
    }

#pragma unroll
    for (int i = 0; i < 4; ++i) {            // reduce across edge groups
        if (F == 64) acc[i] += __shfl_xor(acc[i], 16);
        acc[i] += __shfl_xor(acc[i], 32);
    }

    if (lane < L) {
        float4 b4 = *(const float4*)(bias + lane * 4);
        float4 o = make_float4(acc[0] + b4.x, acc[1] + b4.y,
                               acc[2] + b4.z, acc[3] + b4.w);
        if (RELU) { o.x = fmaxf(o.x, 0.f); o.y = fmaxf(o.y, 0.f);
                    o.z = fmaxf(o.z, 0.f); o.w = fmaxf(o.w, 0.f); }
        if (OUTBF) {                          // bf16 row-major (GEMM2 A input)
            u16* out = (u16*)outp;
            *(ushort4*)(out + (size_t)node * F + lane * 4) =
                make_ushort4(f2bf(o.x), f2bf(o.y), f2bf(o.z), f2bf(o.w));
        } else {                              // fp32 row-major (final output)
            float* out = (float*)outp;
            *(float4*)(out + (size_t)node * F + lane * 4) = o;
        }
    }
}

// ---------------- launch ----------------

extern "C" void kernel_launch(void* const* d_in, const int* in_sizes, int n_in,
                              void* d_out, int out_size, void* d_ws, size_t ws_size,
                              hipStream_t stream) {
    const float* x  = (const float*)d_in[0];
    const int*   ei = (const int*)d_in[1];
    const float* W1 = (const float*)d_in[2];
    const float* b1 = (const float*)d_in[3];
    const float* W2 = (const float*)d_in[4];
    const float* b2 = (const float*)d_in[5];
    float* out = (float*)d_out;

    char* ws = (char*)d_ws;
    size_t off = 0;
    int* cnt = (int*)ws;                     off += (size_t)2 * NPAD * 4;
    u16* ell = (u16*)(ws + off);             off += (size_t)NN * CAP * 2;
    off = (off + 255) & ~(size_t)255;
    u16* W1h = (u16*)(ws + off);             off += 16384 * 2;
    u16* W1l = (u16*)(ws + off);             off += 16384 * 2;
    u16* W2h = (u16*)(ws + off);             off += 8192 * 2;
    u16* W2l = (u16*)(ws + off);             off += 8192 * 2;
    off = (off + 255) & ~(size_t)255;
    u16* els = (u16*)(ws + off);             off += (size_t)NN * 64 * 2;
    float* nrm = (float*)(ws + off);         off += (size_t)NN * 64 * 4;
    int* mArr = (int*)(ws + off);            off += (size_t)NN * 4;
    u16* degT = (u16*)(ws + off);            off += (size_t)NN * 2;
    off = (off + 255) & ~(size_t)255;
    float* H1f = (float*)(ws + off);         off += (size_t)NN * 128 * 4;
    u16*   Abf = (u16*)(ws + off);           off += (size_t)NN * 128 * 2;
    float* H2f = (float*)(ws + off);         off += (size_t)NN * 64 * 4;

    prep_w<<<128, 256, 0, stream>>>(W1, W2, W1h, W1l, W2h, W2l, cnt);
    build_ell<<<1600, 256, 0, stream>>>(ei, cnt, ell);

    // layer 1: H1 = x@W1 (fp32 out) + degT epilogue
    gemm_mfma1<<<(NN + 63) / 64, 256, 0, stream>>>(x, W1h, W1l, H1f, NN, cnt, degT);
    // one-shot per-edge (src, norm) compaction
    build_norm<<<(NN + 3) / 4, 256, 0, stream>>>(cnt, ell, degT, els, nrm, mArr);
    // agg+bias+relu -> Abf (bf16 row-major, GEMM2 A)
    aggregate_f<128, true, true><<<(NN + 3) / 4, 256, 0, stream>>>(
        H1f, els, nrm, mArr, b1, Abf);

    // layer 2: H2 = Abf@W2 (bf16 exact 2-term, fp32 out)
    gemm_mfma_bf<<<(NN + 63) / 64, 256, 0, stream>>>(Abf, W2h, W2l, H2f, NN);
    // agg+bias -> out (fp32 row-major)
    aggregate_f<64, false, false><<<(NN + 3) / 4, 256, 0, stream>>>(
        H2f, els, nrm, mArr, b2, out);
}

// Round 3
// 197.290 us; speedup vs baseline: 1.2447x; 1.2183x over previous
//
#include <hip/hip_runtime.h>

#define NN 50000
#define NE 800000
#define CAP 64        // 2 shards x 32 slots
#define NPAD 50176    // counter array stride (line-separated shards)
#define SLICE 6250    // NN / 8 nodes per XCD slice

typedef unsigned int   u32;
typedef unsigned short u16;
typedef __attribute__((ext_vector_type(8))) short short8;  // 8 bf16 in 4 VGPRs
typedef __attribute__((ext_vector_type(4))) float f32x4;

__device__ inline u16 f2bf(float f) {
    u32 u = __float_as_uint(f);
    return (u16)((u + 0x7FFF + ((u >> 16) & 1)) >> 16);   // RNE
}
__device__ inline float bfval(u16 h) { return __uint_as_float(((u32)h) << 16); }
__device__ inline float bf_lo(u32 u) { return __uint_as_float(u << 16); }
__device__ inline float bf_hi(u32 u) { return __uint_as_float(u & 0xFFFF0000u); }

// ---------------- graph build (XCD-sliced, 2-way sharded counters) ----------

__global__ __launch_bounds__(256) void build_ell(const int* __restrict__ ei,
                                                 int* __restrict__ cnt,
                                                 u16* __restrict__ ell) {
    const int s  = blockIdx.x & 7;
    const int g  = blockIdx.x >> 3;
    const int ng = gridDim.x >> 3;
    const int lo = s * SLICE, hi = lo + SLICE;
    for (int e0 = (g * 256 + (int)threadIdx.x) * 4; e0 < NE; e0 += ng * 1024) {
        int4 d4 = *(const int4*)(ei + NE + e0);
        int dv[4] = {d4.x, d4.y, d4.z, d4.w};
#pragma unroll
        for (int k = 0; k < 4; ++k) {
            int d = dv[k];
            if (d >= lo && d < hi) {
                int src = ei[e0 + k];
                int sh = k & 1;
                int pos = atomicAdd(&cnt[sh * NPAD + d], 1);
                if (pos < 32) ell[d * CAP + sh * 32 + pos] = (u16)src;
            }
        }
    }
}

// ---------------- W pre-swizzle + counter zeroing ----------------

__global__ __launch_bounds__(256) void prep_w(const float* __restrict__ W1,
                                              const float* __restrict__ W2,
                                              u16* __restrict__ W1h, u16* __restrict__ W1l,
                                              u16* __restrict__ W2h, u16* __restrict__ W2l,
                                              int* __restrict__ cnt) {
    int i = blockIdx.x * 256 + threadIdx.x;           // grid 128 -> 32768 threads
    for (int z = i; z < 2 * NPAD; z += 32768) cnt[z] = 0;
    const float* W; u16 *Dh, *Dl; int NOUT, idx;
    if (i < 16384) { W = W1; Dh = W1h; Dl = W1l; NOUT = 128; idx = i; }
    else           { idx = i - 16384; if (idx >= 8192) return;
                     W = W2; Dh = W2h; Dl = W2l; NOUT = 64; }
    int j = idx & 7, l = (idx >> 3) & 63, kc = (idx >> 9) & 3, t = idx >> 11;
    int k = kc * 32 + (l >> 4) * 8 + j;
    int n = t * 16 + (l & 15);
    float w = W[k * NOUT + n];
    u16 h = f2bf(w);
    Dh[idx] = h;
    Dl[idx] = f2bf(w - bfval(h));
}

// ---------------- MFMA GEMM, K=128, fp32 A via 3-term bf16 split ------------
// bf16 C row-major [M][128]. degT epilogue: total degree (+self) per node.

__global__ __launch_bounds__(256) void gemm_mfma1(const float* __restrict__ A,
                                                  const u16* __restrict__ Wh,
                                                  const u16* __restrict__ Wl,
                                                  u16* __restrict__ C, int M,
                                                  const int* __restrict__ cnt,
                                                  u16* __restrict__ degT) {
    constexpr int NT = 8;
    const int tid = threadIdx.x;

    if (tid < 64) {                       // independent degT epilogue (free)
        int node = blockIdx.x * 64 + tid;
        if (node < NN) degT[node] = (u16)(cnt[node] + cnt[NPAD + node] + 1);
    }

    const int w = tid >> 6, l = tid & 63;
    const int m = l & 15, q = l >> 4;

    int arow = blockIdx.x * 64 + w * 16 + m;
    const float* Ar = A + (size_t)min(arow, M - 1) * 128;

    f32x4 acc[NT] = {};

#pragma unroll
    for (int kc = 0; kc < 4; ++kc) {
        float p[8];
        *(float4*)&p[0] = *(const float4*)(Ar + kc * 32 + q * 8);
        *(float4*)&p[4] = *(const float4*)(Ar + kc * 32 + q * 8 + 4);
        short8 ah, al;
#pragma unroll
        for (int j = 0; j < 8; ++j) {
            u16 h = f2bf(p[j]);
            ah[j] = (short)h;
            al[j] = (short)f2bf(p[j] - bfval(h));
        }
#pragma unroll
        for (int t = 0; t < NT; ++t) {
            size_t bo = ((size_t)(t * 4 + kc) * 64 + l) * 8;
            short8 bh = *(const short8*)(Wh + bo);
            short8 bl = *(const short8*)(Wl + bo);
            acc[t] = __builtin_amdgcn_mfma_f32_16x16x32_bf16(ah, bh, acc[t], 0, 0, 0);
            acc[t] = __builtin_amdgcn_mfma_f32_16x16x32_bf16(al, bh, acc[t], 0, 0, 0);
            acc[t] = __builtin_amdgcn_mfma_f32_16x16x32_bf16(ah, bl, acc[t], 0, 0, 0);
        }
    }

    int growbase = blockIdx.x * 64 + w * 16 + q * 4;
#pragma unroll
    for (int t = 0; t < NT; ++t)
#pragma unroll
        for (int r = 0; r < 4; ++r) {
            int grow = growbase + r;
            if (grow < M) C[(size_t)grow * 128 + t * 16 + m] = f2bf(acc[t][r]);
        }
}

// ---- MFMA GEMM, K=128, bf16 A (exact 2-term), bf16 out [M][64] -------------

__global__ __launch_bounds__(256) void gemm_mfma_bf(const u16* __restrict__ A,
                                                    const u16* __restrict__ Wh,
                                                    const u16* __restrict__ Wl,
                                                    u16* __restrict__ C, int M) {
    constexpr int NT = 4;
    const int tid = threadIdx.x;
    const int w = tid >> 6, l = tid & 63;
    const int m = l & 15, q = l >> 4;

    int arow = blockIdx.x * 64 + w * 16 + m;
    const u16* Ar = A + (size_t)min(arow, M - 1) * 128;

    f32x4 acc[NT] = {};

#pragma unroll
    for (int kc = 0; kc < 4; ++kc) {
        short8 ah = *(const short8*)(Ar + kc * 32 + q * 8);
#pragma unroll
        for (int t = 0; t < NT; ++t) {
            size_t bo = ((size_t)(t * 4 + kc) * 64 + l) * 8;
            short8 bh = *(const short8*)(Wh + bo);
            short8 bl = *(const short8*)(Wl + bo);
            acc[t] = __builtin_amdgcn_mfma_f32_16x16x32_bf16(ah, bh, acc[t], 0, 0, 0);
            acc[t] = __builtin_amdgcn_mfma_f32_16x16x32_bf16(ah, bl, acc[t], 0, 0, 0);
        }
    }

    int growbase = blockIdx.x * 64 + w * 16 + q * 4;
#pragma unroll
    for (int t = 0; t < NT; ++t)
#pragma unroll
        for (int r = 0; r < 4; ++r) {
            int grow = growbase + r;
            if (grow < M) C[(size_t)grow * 64 + t * 16 + m] = f2bf(acc[t][r]);
        }
}

// ---------------- normalized aggregation (one wave per node, bf16 H) --------
// Grid-stride (2048 blocks = 32 waves/CU). Inline norm via degT (1 scattered
// u16 read per lane, once per node). Software-pipelined gather: next edge
// group's uint4 load issues before consuming the current one (2 in flight).
// Lanes beyond the valid slot count carry n=0 / s=node (dup-line gathers).

template <int F, bool RELU, bool OUTBF>
__global__ __launch_bounds__(256) void aggregate_bf(const u16* __restrict__ H,
                                                    const u16* __restrict__ ell,
                                                    const int* __restrict__ cnt,
                                                    const u16* __restrict__ degT,
                                                    const float* __restrict__ bias,
                                                    void* __restrict__ outp) {
    const int tid = threadIdx.x;
    const int lane = tid & 63;
    const int wid = (int)((blockIdx.x * 256 + tid) >> 6);
    const int nw = (int)((gridDim.x * 256) >> 6);

    constexpr int L = F / 8;          // lanes per edge (uint4 = 8 bf16): 16 / 8
    constexpr int G = 64 / L;         // edges per gather group: 4 / 8
    const int g = lane / L;
    const int ci = lane & (L - 1);

    for (int node = wid; node < NN; node += nw) {
        const int c0r = cnt[node], c1r = cnt[NPAD + node];
        const int c0 = min(c0r, 32), c1 = min(c1r, 32);
        const int ne = min(c0 + c1, 63);          // slot ne = self-loop
        const float di = rsqrtf((float)(c0r + c1r + 1));
        int slot = (lane < c0) ? lane : 32 + (lane - c0);
        int   s_l = (lane < ne) ? (int)ell[(size_t)node * CAP + slot] : node;
        float n_l = (lane <= ne) ? rsqrtf((float)degT[s_l]) * di : 0.0f;

        const int ng = (ne + G) / G;              // ceil((ne+1)/G) groups

        int   sC = __shfl(s_l, g);
        float nC = __shfl(n_l, g);
        uint4 vC = *(const uint4*)(H + (size_t)sC * F + ci * 8);

        float acc[8] = {0, 0, 0, 0, 0, 0, 0, 0};
        for (int gi = 0; gi < ng; ++gi) {
            int gn = min(gi + 1, ng - 1);         // dup prefetch on last iter
            int   sN = __shfl(s_l, gn * G + g);
            float nN = __shfl(n_l, gn * G + g);
            uint4 vN = *(const uint4*)(H + (size_t)sN * F + ci * 8);
            acc[0] += nC * bf_lo(vC.x); acc[1] += nC * bf_hi(vC.x);
            acc[2] += nC * bf_lo(vC.y); acc[3] += nC * bf_hi(vC.y);
            acc[4] += nC * bf_lo(vC.z); acc[5] += nC * bf_hi(vC.z);
            acc[6] += nC * bf_lo(vC.w); acc[7] += nC * bf_hi(vC.w);
            vC = vN;
            nC = (gi + 1 < ng) ? nN : 0.0f;       // never consume the dup
        }

#pragma unroll
        for (int i = 0; i < 8; ++i) {             // reduce across edge groups
            if (L <= 8) acc[i] += __shfl_xor(acc[i], 8);
            acc[i] += __shfl_xor(acc[i], 16);
            acc[i] += __shfl_xor(acc[i], 32);
        }

        if (lane < L) {                           // lane covers feats [8l,8l+8)
            float4 b0 = *(const float4*)(bias + lane * 8);
            float4 b1 = *(const float4*)(bias + lane * 8 + 4);
            float o[8] = {acc[0] + b0.x, acc[1] + b0.y, acc[2] + b0.z,
                          acc[3] + b0.w, acc[4] + b1.x, acc[5] + b1.y,
                          acc[6] + b1.z, acc[7] + b1.w};
            if (RELU)
#pragma unroll
                for (int k = 0; k < 8; ++k) o[k] = fmaxf(o[k], 0.f);
            if (OUTBF) {                          // bf16 row-major
                union { ushort4 s4[2]; uint4 q; } pk;
                pk.s4[0] = make_ushort4(f2bf(o[0]), f2bf(o[1]), f2bf(o[2]), f2bf(o[3]));
                pk.s4[1] = make_ushort4(f2bf(o[4]), f2bf(o[5]), f2bf(o[6]), f2bf(o[7]));
                *(uint4*)((u16*)outp + (size_t)node * F + lane * 8) = pk.q;
            } else {                              // fp32 row-major (final out)
                float* out = (float*)outp + (size_t)node * F + lane * 8;
                *(float4*)out = make_float4(o[0], o[1], o[2], o[3]);
                *(float4*)(out + 4) = make_float4(o[4], o[5], o[6], o[7]);
            }
        }
    }
}

// ---------------- launch ----------------

extern "C" void kernel_launch(void* const* d_in, const int* in_sizes, int n_in,
                              void* d_out, int out_size, void* d_ws, size_t ws_size,
                              hipStream_t stream) {
    const float* x  = (const float*)d_in[0];
    const int*   ei = (const int*)d_in[1];
    const float* W1 = (const float*)d_in[2];
    const float* b1 = (const float*)d_in[3];
    const float* W2 = (const float*)d_in[4];
    const float* b2 = (const float*)d_in[5];
    float* out = (float*)d_out;

    char* ws = (char*)d_ws;
    size_t off = 0;
    int* cnt = (int*)ws;                     off += (size_t)2 * NPAD * 4;
    u16* ell = (u16*)(ws + off);             off += (size_t)NN * CAP * 2;
    off = (off + 255) & ~(size_t)255;
    u16* W1h = (u16*)(ws + off);             off += 16384 * 2;
    u16* W1l = (u16*)(ws + off);             off += 16384 * 2;
    u16* W2h = (u16*)(ws + off);             off += 8192 * 2;
    u16* W2l = (u16*)(ws + off);             off += 8192 * 2;
    off = (off + 255) & ~(size_t)255;
    u16* degT = (u16*)(ws + off);            off += (size_t)NPAD * 2;
    off = (off + 255) & ~(size_t)255;
    u16* Hbf = (u16*)(ws + off);             off += (size_t)NN * 128 * 2;  // H1
    u16* Abf = (u16*)(ws + off);             off += (size_t)NN * 128 * 2;  // agg1
    u16* H2b = (u16*)(ws + off);             off += (size_t)NN * 64 * 2;   // H2

    prep_w<<<128, 256, 0, stream>>>(W1, W2, W1h, W1l, W2h, W2l, cnt);
    build_ell<<<1600, 256, 0, stream>>>(ei, cnt, ell);

    // layer 1: H1 = x@W1 (bf16) + degT epilogue ; agg+bias+relu -> Abf (bf16)
    gemm_mfma1<<<(NN + 63) / 64, 256, 0, stream>>>(x, W1h, W1l, Hbf, NN, cnt, degT);
    aggregate_bf<128, true, true><<<2048, 256, 0, stream>>>(
        Hbf, ell, cnt, degT, b1, Abf);

    // layer 2: H2 = Abf@W2 (bf16 exact 2-term) ; agg+bias -> out (fp32)
    gemm_mfma_bf<<<(NN + 63) / 64, 256, 0, stream>>>(Abf, W2h, W2l, H2b, NN);
    aggregate_bf<64, false, false><<<2048, 256, 0, stream>>>(
        H2b, ell, cnt, degT, b2, out);
}